// Round 1
// baseline (1989.020 us; speedup 1.0000x reference)
//
#include <hip/hip_runtime.h>
#include <stdint.h>

#define GAS __attribute__((address_space(1)))
#define LAS __attribute__((address_space(3)))

typedef __bf16 bf16x8 __attribute__((ext_vector_type(8)));
typedef float f32x4 __attribute__((ext_vector_type(4)));
typedef _Float16 h2v __attribute__((ext_vector_type(2)));
typedef _Float16 h8v __attribute__((ext_vector_type(8)));

__device__ __forceinline__ unsigned short f2bf(float f) {
  unsigned u = __float_as_uint(f);
  unsigned r = (u + 0x7FFFu + ((u >> 16) & 1u)) >> 16;
  return (unsigned short)r;
}

#if defined(__has_builtin)
#if __has_builtin(__builtin_amdgcn_fdot2)
#define HAVE_FDOT2 1
#endif
#endif

__device__ __forceinline__ float fdot2(h2v a, h2v b, float c) {
#ifdef HAVE_FDOT2
  return __builtin_amdgcn_fdot2(a, b, c, false);
#else
  return c + (float)a[0] * (float)b[0] + (float)a[1] * (float)b[1];
#endif
}

__device__ __forceinline__ float sigmoidf(float x) {
  return 1.f / (1.f + expf(-x));
}

// ---------------- gather: x_bf16 [4096,512] from seq; word_emb f32 [64,512] ----
__global__ __launch_bounds__(128) void k_gather(
    const float* __restrict__ emb, const int* __restrict__ seq,
    const int* __restrict__ word, unsigned short* __restrict__ xbf,
    float* __restrict__ wemb) {
  int row = blockIdx.x;
  int tid = threadIdx.x;
  if (row < 4096) {
    const float* src = emb + (size_t)seq[row] * 512;
    unsigned short* dst = xbf + (size_t)row * 512;
    for (int e = tid; e < 512; e += 128) dst[e] = f2bf(src[e]);
  } else {
    int b = row - 4096;
    const float* src = emb + (size_t)word[b] * 512;
    float* dst = wemb + (size_t)b * 512;
    for (int e = tid; e < 512; e += 128) dst[e] = src[e];
  }
}

// ---------------- weight conversion -------------------------------------------
// wih_bf  [1536,512] bf16 (row-major, K contiguous)
// whh_t   [64][1536] of half8: element ((k>>3)*1536 + o)*8 + (k&7)
// wzrh_t  same shape; rows: 0-511 zt_W[:,512:], 512-1023 rt_W[:,512:], 1024-1535 ht_W[:,512:]
// whta_t  [64][512] of half8: ht_W[:, :512]
// dec_bf  [32000,512] bf16
__global__ __launch_bounds__(128) void k_conv(
    const float* __restrict__ Wih, const float* __restrict__ Whh,
    const float* __restrict__ ztW, const float* __restrict__ rtW,
    const float* __restrict__ htW, const float* __restrict__ decW,
    unsigned short* __restrict__ wih_bf, _Float16* __restrict__ whh_t,
    _Float16* __restrict__ wzrh_t, _Float16* __restrict__ whta_t,
    unsigned short* __restrict__ dec_bf) {
  int row = blockIdx.x;
  int tid = threadIdx.x;
  if (row < 1536) {
    const float* s = Wih + (size_t)row * 512;
    unsigned short* d = wih_bf + (size_t)row * 512;
    for (int e = tid; e < 512; e += 128) d[e] = f2bf(s[e]);
  } else if (row < 3072) {
    int o = row - 1536;
    const float* s = Whh + (size_t)o * 512;
    for (int e = tid; e < 512; e += 128)
      whh_t[((size_t)(e >> 3) * 1536 + o) * 8 + (e & 7)] = (_Float16)s[e];
  } else if (row < 4608) {
    int o = row - 3072;
    const float* s;
    if (o < 512) s = ztW + (size_t)o * 1024 + 512;
    else if (o < 1024) s = rtW + (size_t)(o - 512) * 1024 + 512;
    else s = htW + (size_t)(o - 1024) * 1024 + 512;
    for (int e = tid; e < 512; e += 128)
      wzrh_t[((size_t)(e >> 3) * 1536 + o) * 8 + (e & 7)] = (_Float16)s[e];
  } else if (row < 5120) {
    int o = row - 4608;
    const float* s = htW + (size_t)o * 1024;
    for (int e = tid; e < 512; e += 128)
      whta_t[((size_t)(e >> 3) * 512 + o) * 8 + (e & 7)] = (_Float16)s[e];
  } else {
    int o = row - 5120;
    const float* s = decW + (size_t)o * 512;
    unsigned short* d = dec_bf + (size_t)o * 512;
    for (int e = tid; e < 512; e += 128) d[e] = f2bf(s[e]);
  }
}

// ---------------- step-invariant gate preactivations from word_emb ------------
__global__ __launch_bounds__(256) void k_pre(
    const float* __restrict__ ztW, const float* __restrict__ ztb,
    const float* __restrict__ rtW, const float* __restrict__ rtb,
    const float* __restrict__ wemb, float* __restrict__ ztp,
    float* __restrict__ rtp) {
  int idx = blockIdx.x * 256 + threadIdx.x;
  int b = idx >> 10, o = idx & 1023;
  const float4* we = (const float4*)(wemb + (size_t)b * 512);
  const float4* wr;
  float acc;
  if (o < 512) { wr = (const float4*)(ztW + (size_t)o * 1024); acc = ztb[o]; }
  else { wr = (const float4*)(rtW + (size_t)(o - 512) * 1024); acc = rtb[o - 512]; }
  for (int c = 0; c < 128; ++c) {
    float4 w = wr[c], e = we[c];
    acc += w.x * e.x + w.y * e.y + w.z * e.z + w.w * e.w;
  }
  if (o < 512) ztp[(size_t)b * 512 + o] = acc;
  else rtp[(size_t)b * 512 + (o - 512)] = acc;
}

// ---------------- bf16 GEMM, C[m,n] = sum_k A[m,k]*B[n,k] + bias[n] ----------
// A [M,K] bf16, B [N,K] bf16, C [M,N] f32. M,N multiples of 128, K of 32.
__global__ __launch_bounds__(256) void k_gemm_bt(
    const unsigned short* __restrict__ A, const unsigned short* __restrict__ B,
    float* __restrict__ C, const float* __restrict__ bias,
    int M, int N, int K) {
  __shared__ __align__(16) unsigned short As[128 * 32];
  __shared__ __align__(16) unsigned short Bs[128 * 32];
  int nt = N >> 7;
  int nwg = gridDim.x;
  int bid = blockIdx.x;
  int swz = (bid & 7) * (nwg >> 3) + (bid >> 3);  // XCD swizzle (nwg % 8 == 0)
  int m0 = (swz / nt) << 7, n0 = (swz % nt) << 7;
  int tid = threadIdx.x;
  int l = tid & 63, w = tid >> 6;
  int wr = w >> 1, wc = w & 1;
  int lr = l & 15, lk = l >> 4;
  f32x4 acc[4][4] = {};
  for (int k0 = 0; k0 < K; k0 += 32) {
#pragma unroll
    for (int i = 0; i < 2; ++i) {
      int c = w * 2 + i;
      int off = c * 1024 + l * 16;
      int row = off >> 6, kb = off & 63;
      const char* ga = (const char*)A + ((size_t)(m0 + row) * K + k0) * 2 + kb;
      const char* gb = (const char*)B + ((size_t)(n0 + row) * K + k0) * 2 + kb;
      __builtin_amdgcn_global_load_lds((const GAS void*)ga,
                                       (LAS void*)((char*)As + c * 1024), 16, 0, 0);
      __builtin_amdgcn_global_load_lds((const GAS void*)gb,
                                       (LAS void*)((char*)Bs + c * 1024), 16, 0, 0);
    }
    asm volatile("s_waitcnt vmcnt(0)" ::: "memory");
    __syncthreads();
    bf16x8 af[4], bfr[4];
#pragma unroll
    for (int i = 0; i < 4; ++i)
      af[i] = *(const bf16x8*)&As[(wr * 64 + i * 16 + lr) * 32 + lk * 8];
#pragma unroll
    for (int i = 0; i < 4; ++i)
      bfr[i] = *(const bf16x8*)&Bs[(wc * 64 + i * 16 + lr) * 32 + lk * 8];
#pragma unroll
    for (int i = 0; i < 4; ++i)
#pragma unroll
      for (int jj = 0; jj < 4; ++jj)
        acc[i][jj] = __builtin_amdgcn_mfma_f32_16x16x32_bf16(af[i], bfr[jj], acc[i][jj], 0, 0, 0);
    __syncthreads();
  }
#pragma unroll
  for (int jj = 0; jj < 4; ++jj) {
    int col = n0 + wc * 64 + jj * 16 + lr;
    float bv = bias ? bias[col] : 0.f;
#pragma unroll
    for (int i = 0; i < 4; ++i) {
      int rb = m0 + wr * 64 + i * 16 + lk * 4;
#pragma unroll
      for (int q = 0; q < 4; ++q)
        C[(size_t)(rb + q) * N + col] = acc[i][jj][q] + bv;
    }
  }
}

// ---------------- recurrence: 1 workgroup per batch element -------------------
__global__ __launch_bounds__(512) void k_rnn(
    const _Float16* __restrict__ whh_t, const _Float16* __restrict__ wzrh_t,
    const _Float16* __restrict__ whta_t, const float* __restrict__ gi,
    const float* __restrict__ ztp, const float* __restrict__ rtp,
    const float* __restrict__ htb, const float* __restrict__ bhh,
    const float* __restrict__ inith, const float* __restrict__ wemb,
    unsigned short* __restrict__ outs, float* __restrict__ hfin) {
  int b = blockIdx.x, j = threadIdx.x;
  __shared__ __align__(16) _Float16 h16[512];
  __shared__ __align__(16) _Float16 hg16[512];
  __shared__ __align__(16) _Float16 rw16[512];
  float we = wemb[(size_t)b * 512 + j];
  float hown = inith[(size_t)b * 512 + j];
  h16[j] = (_Float16)hown;
  float zpre = ztp[(size_t)b * 512 + j];
  float rpre = rtp[(size_t)b * 512 + j];
  float br = bhh[j], bz = bhh[512 + j], bn = bhh[1024 + j];
  float bht = htb[j];
  __syncthreads();
  for (int t = 0; t < 64; ++t) {
    const float* git = gi + ((size_t)t * 64 + b) * 1536;
    float ir = git[j], iz = git[512 + j], inn = git[1024 + j];
    // phase 1: gh = W_hh @ h ; build h_gru
    float hr = br, hz = bz, hn = bn;
    {
      const h8v* hv8 = (const h8v*)h16;
      const h8v* W = (const h8v*)whh_t;
#pragma unroll 4
      for (int c = 0; c < 64; ++c) {
        h8v hv = hv8[c];
        h8v a0 = W[(size_t)c * 1536 + j];
        h8v a1 = W[(size_t)c * 1536 + 512 + j];
        h8v a2 = W[(size_t)c * 1536 + 1024 + j];
        const h2v* hp = (const h2v*)&hv;
        const h2v* p0 = (const h2v*)&a0;
        const h2v* p1 = (const h2v*)&a1;
        const h2v* p2 = (const h2v*)&a2;
#pragma unroll
        for (int q = 0; q < 4; ++q) {
          hr = fdot2(hp[q], p0[q], hr);
          hz = fdot2(hp[q], p1[q], hz);
          hn = fdot2(hp[q], p2[q], hn);
        }
      }
    }
    float r = sigmoidf(ir + hr);
    float z = sigmoidf(iz + hz);
    float n = tanhf(inn + r * hn);
    float hg = (1.f - z) * n + z * hown;
    hg16[j] = (_Float16)hg;
    outs[((size_t)t * 64 + b) * 512 + j] = f2bf(hg);
    __syncthreads();
    // phase 2: zt, rt, htB from h_gru
    float za = zpre, ra = rpre, ha = 0.f;
    {
      const h8v* hv8 = (const h8v*)hg16;
      const h8v* W = (const h8v*)wzrh_t;
#pragma unroll 4
      for (int c = 0; c < 64; ++c) {
        h8v hv = hv8[c];
        h8v a0 = W[(size_t)c * 1536 + j];
        h8v a1 = W[(size_t)c * 1536 + 512 + j];
        h8v a2 = W[(size_t)c * 1536 + 1024 + j];
        const h2v* hp = (const h2v*)&hv;
        const h2v* p0 = (const h2v*)&a0;
        const h2v* p1 = (const h2v*)&a1;
        const h2v* p2 = (const h2v*)&a2;
#pragma unroll
        for (int q = 0; q < 4; ++q) {
          za = fdot2(hp[q], p0[q], za);
          ra = fdot2(hp[q], p1[q], ra);
          ha = fdot2(hp[q], p2[q], ha);
        }
      }
    }
    float zt = sigmoidf(za);
    float rt = sigmoidf(ra);
    rw16[j] = (_Float16)(rt * we);
    __syncthreads();
    // phase 3: htA = ht_W[:, :E] @ (rt*word_emb) ; h_new
    float hA = 0.f;
    {
      const h8v* rv8 = (const h8v*)rw16;
      const h8v* W = (const h8v*)whta_t;
#pragma unroll 4
      for (int c = 0; c < 64; ++c) {
        h8v rv = rv8[c];
        h8v aw = W[(size_t)c * 512 + j];
        const h2v* rp = (const h2v*)&rv;
        const h2v* p0 = (const h2v*)&aw;
#pragma unroll
        for (int q = 0; q < 4; ++q) hA = fdot2(rp[q], p0[q], hA);
      }
    }
    float htl = tanhf(hA + ha + bht);
    hown = (1.f - zt) * hg + zt * htl;
    h16[j] = (_Float16)hown;
    __syncthreads();
  }
  hfin[(size_t)b * 512 + j] = hown;
}

extern "C" void kernel_launch(void* const* d_in, const int* in_sizes, int n_in,
                              void* d_out, int out_size, void* d_ws, size_t ws_size,
                              hipStream_t stream) {
  const float* emb   = (const float*)d_in[0];
  const float* Wih   = (const float*)d_in[1];
  const float* Whh   = (const float*)d_in[2];
  const float* bih   = (const float*)d_in[3];
  const float* bhh   = (const float*)d_in[4];
  const float* ztW   = (const float*)d_in[5];
  const float* ztb   = (const float*)d_in[6];
  const float* rtW   = (const float*)d_in[7];
  const float* rtb   = (const float*)d_in[8];
  const float* htW   = (const float*)d_in[9];
  const float* htb   = (const float*)d_in[10];
  const float* decW  = (const float*)d_in[11];
  const float* decb  = (const float*)d_in[12];
  const float* inith = (const float*)d_in[13];
  const int* word    = (const int*)d_in[14];
  const int* seq     = (const int*)d_in[15];
  float* out = (float*)d_out;

  char* ws = (char*)d_ws;
  size_t off = 0;
  auto alloc = [&](size_t bytes) {
    size_t o = off;
    off += (bytes + 255) & ~(size_t)255;
    return o;
  };
  unsigned short* xbf   = (unsigned short*)(ws + alloc(4096ull * 512 * 2));
  unsigned short* wihbf = (unsigned short*)(ws + alloc(1536ull * 512 * 2));
  _Float16* whh_t       = (_Float16*)(ws + alloc(1536ull * 512 * 2));
  _Float16* wzrh_t      = (_Float16*)(ws + alloc(1536ull * 512 * 2));
  _Float16* whta_t      = (_Float16*)(ws + alloc(512ull * 512 * 2));
  unsigned short* decbf = (unsigned short*)(ws + alloc(32000ull * 512 * 2));
  float* wemb           = (float*)(ws + alloc(64ull * 512 * 4));
  float* ztp            = (float*)(ws + alloc(64ull * 512 * 4));
  float* rtp            = (float*)(ws + alloc(64ull * 512 * 4));
  float* gi             = (float*)(ws + alloc(4096ull * 1536 * 4));
  unsigned short* outsb = (unsigned short*)(ws + alloc(4096ull * 512 * 2));

  hipLaunchKernelGGL(k_gather, dim3(4160), dim3(128), 0, stream,
                     emb, seq, word, xbf, wemb);
  hipLaunchKernelGGL(k_conv, dim3(37120), dim3(128), 0, stream,
                     Wih, Whh, ztW, rtW, htW, decW, wihbf, whh_t, wzrh_t, whta_t, decbf);
  hipLaunchKernelGGL(k_pre, dim3(256), dim3(256), 0, stream,
                     ztW, ztb, rtW, rtb, wemb, ztp, rtp);
  hipLaunchKernelGGL(k_gemm_bt, dim3(384), dim3(256), 0, stream,
                     xbf, wihbf, gi, bih, 4096, 1536, 512);
  hipLaunchKernelGGL(k_rnn, dim3(64), dim3(512), 0, stream,
                     whh_t, wzrh_t, whta_t, gi, ztp, rtp, htb, bhh, inith, wemb,
                     outsb, out + 4096ull * 32000);
  hipLaunchKernelGGL(k_gemm_bt, dim3(8000), dim3(256), 0, stream,
                     outsb, decbf, out, decb, 4096, 32000, 512);
}